// Round 1
// baseline (738.345 us; speedup 1.0000x reference)
//
#include <hip/hip_runtime.h>
#include <hip/hip_bf16.h>

typedef unsigned short u16;
typedef __attribute__((ext_vector_type(4))) float f32x4;
typedef __attribute__((ext_vector_type(8))) short bf16x8;

// ---------------------------------------------------------------------------
// helpers
// ---------------------------------------------------------------------------
__device__ __forceinline__ u16 f2bf(float f) {
    union { float f; unsigned u; } v; v.f = f;
    unsigned r = (v.u + 0x7fffu + ((v.u >> 16) & 1u)) >> 16;   // RNE
    return (u16)r;
}

__device__ __forceinline__ float softplus(float x) {
    // inputs are ~0.1*N(0,1); guard anyway for large x
    return (x > 15.f) ? x : log1pf(__expf(x));
}

__device__ __forceinline__ void gload_lds16(const void* g, void* l) {
    __builtin_amdgcn_global_load_lds(
        (__attribute__((address_space(1))) void*)(g),
        (__attribute__((address_space(3))) void*)(l),
        16, 0, 0);
}

// ---------------------------------------------------------------------------
// prep kernels: fp32 -> bf16 conversions + fused softplus reparameterization
// ---------------------------------------------------------------------------
__global__ __launch_bounds__(256) void prep_x_kernel(
        const float* __restrict__ x, u16* __restrict__ xb, int n4) {
    int i = blockIdx.x * 256 + threadIdx.x;
    if (i >= n4) return;
    float4 v = ((const float4*)x)[i];
    ushort4 o;
    o.x = f2bf(v.x); o.y = f2bf(v.y); o.z = f2bf(v.z); o.w = f2bf(v.w);
    ((ushort4*)xb)[i] = o;
}

__global__ __launch_bounds__(256) void prep_w_kernel(
        const float* __restrict__ mu, const float* __restrict__ rho,
        const float* __restrict__ eps, u16* __restrict__ wb, int n4) {
    int i = blockIdx.x * 256 + threadIdx.x;
    if (i >= n4) return;
    float4 m = ((const float4*)mu)[i];
    float4 r = ((const float4*)rho)[i];
    float4 e = ((const float4*)eps)[i];
    ushort4 o;
    o.x = f2bf(m.x + softplus(r.x) * e.x);
    o.y = f2bf(m.y + softplus(r.y) * e.y);
    o.z = f2bf(m.z + softplus(r.z) * e.z);
    o.w = f2bf(m.w + softplus(r.w) * e.w);
    ((ushort4*)wb)[i] = o;
}

__global__ __launch_bounds__(256) void prep_bias_kernel(
        const float* __restrict__ mu, const float* __restrict__ rho,
        const float* __restrict__ eps, float* __restrict__ b, int n) {
    int i = blockIdx.x * 256 + threadIdx.x;
    if (i < n) b[i] = mu[i] + softplus(rho[i]) * eps[i];
}

// ---------------------------------------------------------------------------
// bf16 B^T GEMM + bias:  C[m][o] = sum_k A[m][k]*B[o][k] + bias[o]
// m97 structure: 128x128 tile, BK=32, 4 waves (2x2 of 64x64),
// mfma_f32_16x16x32_bf16, global_load_lds width=16, linear LDS.
// ---------------------------------------------------------------------------
__global__ __launch_bounds__(256, 2) void gemm_bt_bias(
        const u16* __restrict__ A,   // [M][K] bf16
        const u16* __restrict__ B,   // [Nout][K] bf16
        const float* __restrict__ bias,
        float* __restrict__ C,       // [M][Nout] fp32
        int M, int Nout, int K) {
    __shared__ __attribute__((aligned(16))) u16 As[128 * 32];
    __shared__ __attribute__((aligned(16))) u16 Bs[128 * 32];

    const int tid  = threadIdx.x;
    const int lane = tid & 63;
    const int wave = tid >> 6;
    const int wm = (wave >> 1) * 64;   // wave row offset in tile
    const int wn = (wave & 1) * 64;    // wave col offset in tile

    const int nbn = Nout >> 7;                 // blocks along N
    const int bm  = blockIdx.x / nbn;          // bn fastest -> A-panel L2 reuse
    const int bn  = blockIdx.x % nbn;
    const int m0 = bm << 7, n0 = bn << 7;

    // staging geometry: tile = 128 rows x 32 cols bf16 = 8192 B = 512 x 16B
    // chunk c: row = c>>2, col-chunk = (c&3)*8 elems; thread does c = tid, tid+256
    const int c0 = tid,       r0 = c0 >> 2, e0 = (c0 & 3) * 8;
    const int c1 = tid + 256, r1 = c1 >> 2, e1 = (c1 & 3) * 8;

    const u16* Ag0 = A + (size_t)(m0 + r0) * K + e0;
    const u16* Ag1 = A + (size_t)(m0 + r1) * K + e1;
    const u16* Bg0 = B + (size_t)(n0 + r0) * K + e0;
    const u16* Bg1 = B + (size_t)(n0 + r1) * K + e1;
    char* Al0 = (char*)As + c0 * 16;
    char* Al1 = (char*)As + c1 * 16;
    char* Bl0 = (char*)Bs + c0 * 16;
    char* Bl1 = (char*)Bs + c1 * 16;

    // fragment read coords (A and B operands both K-major rows)
    const int frow = lane & 15;
    const int fk   = (lane >> 4) * 8;

    f32x4 acc[4][4] = {};

    for (int k0 = 0; k0 < K; k0 += 32) {
        gload_lds16(Ag0 + k0, Al0);
        gload_lds16(Ag1 + k0, Al1);
        gload_lds16(Bg0 + k0, Bl0);
        gload_lds16(Bg1 + k0, Bl1);
        __syncthreads();   // compiler emits vmcnt(0) drain before barrier

        bf16x8 af[4], bfv[4];
#pragma unroll
        for (int i = 0; i < 4; ++i)
            af[i] = *(const bf16x8*)&As[(wm + i * 16 + frow) * 32 + fk];
#pragma unroll
        for (int j = 0; j < 4; ++j)
            bfv[j] = *(const bf16x8*)&Bs[(wn + j * 16 + frow) * 32 + fk];

#pragma unroll
        for (int i = 0; i < 4; ++i)
#pragma unroll
            for (int j = 0; j < 4; ++j)
                acc[i][j] = __builtin_amdgcn_mfma_f32_16x16x32_bf16(
                    af[i], bfv[j], acc[i][j], 0, 0, 0);

        __syncthreads();   // protect LDS before next stage
    }

    // epilogue: C/D layout col = lane&15, row = (lane>>4)*4 + reg
    const int crow = (lane >> 4) * 4;
    const int ccol = lane & 15;
#pragma unroll
    for (int i = 0; i < 4; ++i) {
#pragma unroll
        for (int j = 0; j < 4; ++j) {
            const int row = m0 + wm + i * 16 + crow;
            const int col = n0 + wn + j * 16 + ccol;
            const float bv = bias[col];
            float* Cp = C + (size_t)row * Nout + col;
#pragma unroll
            for (int q = 0; q < 4; ++q)
                Cp[(size_t)q * Nout] = acc[i][j][q] + bv;
        }
    }
}

// ---------------------------------------------------------------------------
// launch
// ---------------------------------------------------------------------------
extern "C" void kernel_launch(void* const* d_in, const int* in_sizes, int n_in,
                              void* d_out, int out_size, void* d_ws, size_t ws_size,
                              hipStream_t stream) {
    const float* x    = (const float*)d_in[0];
    const float* wmu  = (const float*)d_in[1];
    const float* wrho = (const float*)d_in[2];
    const float* bmu  = (const float*)d_in[3];
    const float* brho = (const float*)d_in[4];
    const float* ew   = (const float*)d_in[5];
    const float* eb   = (const float*)d_in[6];
    float* out = (float*)d_out;

    const int Nout = in_sizes[3];            // 4096
    const int K    = in_sizes[1] / Nout;     // 4096
    const int M    = in_sizes[0] / K;        // 16384

    // workspace layout: xb[M*K] bf16 | wb[Nout*K] bf16 | bias[Nout] f32
    u16* xb = (u16*)d_ws;
    u16* wb = xb + (size_t)M * K;
    float* bs = (float*)(wb + (size_t)Nout * K);

    const int nx4 = (M * K) / 4;
    const int nw4 = (Nout * K) / 4;
    prep_x_kernel<<<(nx4 + 255) / 256, 256, 0, stream>>>(x, xb, nx4);
    prep_w_kernel<<<(nw4 + 255) / 256, 256, 0, stream>>>(wmu, wrho, ew, wb, nw4);
    prep_bias_kernel<<<(Nout + 255) / 256, 256, 0, stream>>>(bmu, brho, eb, bs, Nout);

    dim3 grid((M / 128) * (Nout / 128));
    gemm_bt_bias<<<grid, 256, 0, stream>>>(xb, wb, bs, out, M, Nout, K);
}

// Round 2
// 572.367 us; speedup vs baseline: 1.2900x; 1.2900x over previous
//
#include <hip/hip_runtime.h>
#include <hip/hip_bf16.h>

typedef unsigned short u16;
typedef __attribute__((ext_vector_type(4))) float f32x4;
typedef __attribute__((ext_vector_type(8))) short bf16x8;

// ---------------------------------------------------------------------------
// helpers
// ---------------------------------------------------------------------------
__device__ __forceinline__ u16 f2bf(float f) {
    union { float f; unsigned u; } v; v.f = f;
    unsigned r = (v.u + 0x7fffu + ((v.u >> 16) & 1u)) >> 16;   // RNE
    return (u16)r;
}

__device__ __forceinline__ float softplus(float x) {
    return (x > 15.f) ? x : log1pf(__expf(x));
}

__device__ __forceinline__ void gload_lds16(const void* g, void* l) {
    __builtin_amdgcn_global_load_lds(
        (__attribute__((address_space(1))) void*)(g),
        (__attribute__((address_space(3))) void*)(l),
        16, 0, 0);
}

#define BAR() do { asm volatile("" ::: "memory"); \
                   __builtin_amdgcn_s_barrier();  \
                   asm volatile("" ::: "memory"); } while (0)

// ---------------------------------------------------------------------------
// prep kernels (unchanged from round 1 — within a few % of BW roofline)
// ---------------------------------------------------------------------------
__global__ __launch_bounds__(256) void prep_x_kernel(
        const float* __restrict__ x, u16* __restrict__ xb, int n4) {
    int i = blockIdx.x * 256 + threadIdx.x;
    if (i >= n4) return;
    float4 v = ((const float4*)x)[i];
    ushort4 o;
    o.x = f2bf(v.x); o.y = f2bf(v.y); o.z = f2bf(v.z); o.w = f2bf(v.w);
    ((ushort4*)xb)[i] = o;
}

__global__ __launch_bounds__(256) void prep_w_kernel(
        const float* __restrict__ mu, const float* __restrict__ rho,
        const float* __restrict__ eps, u16* __restrict__ wb, int n4) {
    int i = blockIdx.x * 256 + threadIdx.x;
    if (i >= n4) return;
    float4 m = ((const float4*)mu)[i];
    float4 r = ((const float4*)rho)[i];
    float4 e = ((const float4*)eps)[i];
    ushort4 o;
    o.x = f2bf(m.x + softplus(r.x) * e.x);
    o.y = f2bf(m.y + softplus(r.y) * e.y);
    o.z = f2bf(m.z + softplus(r.z) * e.z);
    o.w = f2bf(m.w + softplus(r.w) * e.w);
    ((ushort4*)wb)[i] = o;
}

__global__ __launch_bounds__(256) void prep_bias_kernel(
        const float* __restrict__ mu, const float* __restrict__ rho,
        const float* __restrict__ eps, float* __restrict__ b, int n) {
    int i = blockIdx.x * 256 + threadIdx.x;
    if (i < n) b[i] = mu[i] + softplus(rho[i]) * eps[i];
}

// ---------------------------------------------------------------------------
// 256x256 8-phase bf16 GEMM (B^T) + bias.
// LDS: 2 dbuf x {A,B} x [256 rows][64 k] bf16 = 128 KiB, st-swizzled:
//   16B-chunk index kc stored at kc ^ (row & 7)  (involution; conflict-free
//   ds_read_b128, staged via inverse-swizzled GLOBAL source + linear LDS dest).
// Per K-tile: 4 phases (C-quadrants, 16 MFMA each); staging 1 half-unit/phase;
// counted vmcnt(4) at phases 4/8 only; raw s_barrier (no vmcnt(0) drain).
// ---------------------------------------------------------------------------
__device__ __forceinline__ bf16x8 ld_frag(const u16* region, int r0, int ks, int lane) {
    int row = r0 + (lane & 15);
    int kc  = (ks * 4 + (lane >> 4)) ^ (row & 7);
    return *(const bf16x8*)((const char*)region + row * 128 + kc * 16);
}

template <int MB, int NB>
__device__ __forceinline__ void mfma_quad(f32x4 (&acc)[8][4],
                                          const bf16x8 (&av)[4][2],
                                          const bf16x8 (&bv)[2][2]) {
#pragma unroll
    for (int ks = 0; ks < 2; ++ks)
#pragma unroll
        for (int mi = 0; mi < 4; ++mi)
#pragma unroll
            for (int ni = 0; ni < 2; ++ni)
                acc[MB + mi][NB + ni] = __builtin_amdgcn_mfma_f32_16x16x32_bf16(
                    av[mi][ks], bv[ni][ks], acc[MB + mi][NB + ni], 0, 0, 0);
}

// stage one half-unit (128 rows x 64 k): 2 x global_load_lds(16B) per thread
#define STAGE(region, h, P, koff) do {                                          \
    gload_lds16(P[h][0] + (koff), (char*)(region) + (h) * 16384 + (w * 2 + 0) * 1024); \
    gload_lds16(P[h][1] + (koff), (char*)(region) + (h) * 16384 + (w * 2 + 1) * 1024); \
} while (0)

__global__ __launch_bounds__(512, 2) void gemm256_8ph(
        const u16* __restrict__ A,   // [M][K] bf16
        const u16* __restrict__ B,   // [Nout][K] bf16
        const float* __restrict__ bias,
        float* __restrict__ C,       // [M][Nout] fp32
        int M, int Nout, int K) {
    __shared__ __attribute__((aligned(16))) u16 smem[4][16384];  // A0,B0,A1,B1
    u16* A0 = smem[0]; u16* B0 = smem[1];
    u16* A1 = smem[2]; u16* B1 = smem[3];

    const int tid  = threadIdx.x;
    const int lane = tid & 63;
    const int w    = tid >> 6;     // wave 0..7
    const int wr   = w >> 2;       // 0..1 -> 128-row slice
    const int wc   = w & 3;        // 0..3 -> 64-col slice

    // bijective XCD swizzle (nwg % 8 == 0 here)
    const int nbn = Nout >> 8;
    const int nwg = (M >> 8) * nbn;
    const int cpx = nwg >> 3;
    const int swz = ((int)blockIdx.x & 7) * cpx + ((int)blockIdx.x >> 3);
    const int m0 = (swz / nbn) << 8;
    const int n0 = (swz % nbn) << 8;

    // per-thread staging source pointers (inverse-swizzled global chunks)
    const u16* PA[2][2]; const u16* PB[2][2];
#pragma unroll
    for (int q = 0; q < 2; ++q) {
        int c   = (w * 2 + q) * 64 + lane;
        int row = c >> 3;
        int kc  = (c & 7) ^ (row & 7);
#pragma unroll
        for (int h = 0; h < 2; ++h) {
            PA[h][q] = A + (size_t)(m0 + h * 128 + row) * K + kc * 8;
            PB[h][q] = B + (size_t)(n0 + h * 128 + row) * K + kc * 8;
        }
    }

    bf16x8 a[4][2], bl[2][2], bh[2][2];
    f32x4 acc[8][4] = {};

    const int NT = K >> 6;    // K-tiles
    const int NI = NT >> 1;   // iterations (2 tiles each)

    // prologue: tile0 -> buf0 (all), tile1 -> buf1 (B units only)
    STAGE(B0, 0, PB, 0);  STAGE(B0, 1, PB, 0);
    STAGE(A0, 0, PA, 0);  STAGE(A0, 1, PA, 0);
    STAGE(B1, 0, PB, 64); STAGE(B1, 1, PB, 64);
    asm volatile("s_waitcnt vmcnt(4)" ::: "memory");   // tile0 landed
    BAR();

#pragma unroll 1
    for (int i = 0; i < NI; ++i) {
        int t2 = 2 * i + 2; if (t2 >= NT) t2 -= NT;
        int t3 = 2 * i + 3; if (t3 >= NT) t3 -= NT;
        const int k1 = (2 * i + 1) << 6;
        const int k2 = t2 << 6;
        const int k3 = t3 << 6;

        // -------- PH1: buf0 q0 (m-lo, n-lo) | stage buf1.A-lo <- tile 2i+1
#pragma unroll
        for (int mi = 0; mi < 4; ++mi)
#pragma unroll
            for (int ks = 0; ks < 2; ++ks)
                a[mi][ks] = ld_frag(A0, wr * 128 + mi * 16, ks, lane);
#pragma unroll
        for (int ni = 0; ni < 2; ++ni)
#pragma unroll
            for (int ks = 0; ks < 2; ++ks)
                bl[ni][ks] = ld_frag(B0, wc * 64 + ni * 16, ks, lane);
        STAGE(A1, 0, PA, k1);
        asm volatile("s_waitcnt lgkmcnt(8)" ::: "memory");
        BAR();
        asm volatile("s_waitcnt lgkmcnt(0)" ::: "memory");
        __builtin_amdgcn_s_setprio(1);
        mfma_quad<0, 0>(acc, a, bl);
        __builtin_amdgcn_s_setprio(0);
        BAR();

        // -------- PH2: buf0 q1 (m-lo, n-hi) | stage buf1.A-hi <- tile 2i+1
#pragma unroll
        for (int ni = 0; ni < 2; ++ni)
#pragma unroll
            for (int ks = 0; ks < 2; ++ks)
                bh[ni][ks] = ld_frag(B0, wc * 64 + 32 + ni * 16, ks, lane);
        STAGE(A1, 1, PA, k1);
        BAR();
        asm volatile("s_waitcnt lgkmcnt(0)" ::: "memory");
        __builtin_amdgcn_s_setprio(1);
        mfma_quad<0, 2>(acc, a, bh);
        __builtin_amdgcn_s_setprio(0);
        BAR();

        // -------- PH3: buf0 q2 (m-hi, n-hi) | stage buf0.B-lo <- tile 2i+2
#pragma unroll
        for (int mi = 0; mi < 4; ++mi)
#pragma unroll
            for (int ks = 0; ks < 2; ++ks)
                a[mi][ks] = ld_frag(A0, wr * 128 + 64 + mi * 16, ks, lane);
        STAGE(B0, 0, PB, k2);
        asm volatile("s_waitcnt lgkmcnt(8)" ::: "memory");
        BAR();
        asm volatile("s_waitcnt lgkmcnt(0)" ::: "memory");
        __builtin_amdgcn_s_setprio(1);
        mfma_quad<4, 2>(acc, a, bh);
        __builtin_amdgcn_s_setprio(0);
        BAR();

        // -------- PH4: buf0 q3 (m-hi, n-lo) | stage buf0.B-hi <- tile 2i+2
        STAGE(B0, 1, PB, k2);
        asm volatile("s_waitcnt vmcnt(4)" ::: "memory");  // tile 2i+1 landed
        BAR();
        __builtin_amdgcn_s_setprio(1);
        mfma_quad<4, 0>(acc, a, bl);
        __builtin_amdgcn_s_setprio(0);
        BAR();

        // -------- PH5: buf1 q0 | stage buf0.A-lo <- tile 2i+2
#pragma unroll
        for (int mi = 0; mi < 4; ++mi)
#pragma unroll
            for (int ks = 0; ks < 2; ++ks)
                a[mi][ks] = ld_frag(A1, wr * 128 + mi * 16, ks, lane);
#pragma unroll
        for (int ni = 0; ni < 2; ++ni)
#pragma unroll
            for (int ks = 0; ks < 2; ++ks)
                bl[ni][ks] = ld_frag(B1, wc * 64 + ni * 16, ks, lane);
        STAGE(A0, 0, PA, k2);
        asm volatile("s_waitcnt lgkmcnt(8)" ::: "memory");
        BAR();
        asm volatile("s_waitcnt lgkmcnt(0)" ::: "memory");
        __builtin_amdgcn_s_setprio(1);
        mfma_quad<0, 0>(acc, a, bl);
        __builtin_amdgcn_s_setprio(0);
        BAR();

        // -------- PH6: buf1 q1 | stage buf0.A-hi <- tile 2i+2
#pragma unroll
        for (int ni = 0; ni < 2; ++ni)
#pragma unroll
            for (int ks = 0; ks < 2; ++ks)
                bh[ni][ks] = ld_frag(B1, wc * 64 + 32 + ni * 16, ks, lane);
        STAGE(A0, 1, PA, k2);
        BAR();
        asm volatile("s_waitcnt lgkmcnt(0)" ::: "memory");
        __builtin_amdgcn_s_setprio(1);
        mfma_quad<0, 2>(acc, a, bh);
        __builtin_amdgcn_s_setprio(0);
        BAR();

        // -------- PH7: buf1 q2 | stage buf1.B-lo <- tile 2i+3
#pragma unroll
        for (int mi = 0; mi < 4; ++mi)
#pragma unroll
            for (int ks = 0; ks < 2; ++ks)
                a[mi][ks] = ld_frag(A1, wr * 128 + 64 + mi * 16, ks, lane);
        STAGE(B1, 0, PB, k3);
        asm volatile("s_waitcnt lgkmcnt(8)" ::: "memory");
        BAR();
        asm volatile("s_waitcnt lgkmcnt(0)" ::: "memory");
        __builtin_amdgcn_s_setprio(1);
        mfma_quad<4, 2>(acc, a, bh);
        __builtin_amdgcn_s_setprio(0);
        BAR();

        // -------- PH8: buf1 q3 | stage buf1.B-hi <- tile 2i+3
        STAGE(B1, 1, PB, k3);
        asm volatile("s_waitcnt vmcnt(4)" ::: "memory");  // tile 2i+2 landed
        BAR();
        __builtin_amdgcn_s_setprio(1);
        mfma_quad<4, 0>(acc, a, bl);
        __builtin_amdgcn_s_setprio(0);
        BAR();
    }

    asm volatile("s_waitcnt vmcnt(0)" ::: "memory");  // drain wrapped prefetch

    // epilogue: C/D layout col = lane&15, row = (lane>>4)*4 + q
    const int crow = (lane >> 4) * 4;
    const int ccol = lane & 15;
#pragma unroll
    for (int mi = 0; mi < 8; ++mi) {
#pragma unroll
        for (int ni = 0; ni < 4; ++ni) {
            const int row = m0 + wr * 128 + mi * 16 + crow;
            const int col = n0 + wc * 64 + ni * 16 + ccol;
            const float bv = bias[col];
            float* Cp = C + (size_t)row * Nout + col;
#pragma unroll
            for (int q = 0; q < 4; ++q)
                Cp[(size_t)q * Nout] = acc[mi][ni][q] + bv;
        }
    }
}

// ---------------------------------------------------------------------------
// launch
// ---------------------------------------------------------------------------
extern "C" void kernel_launch(void* const* d_in, const int* in_sizes, int n_in,
                              void* d_out, int out_size, void* d_ws, size_t ws_size,
                              hipStream_t stream) {
    const float* x    = (const float*)d_in[0];
    const float* wmu  = (const float*)d_in[1];
    const float* wrho = (const float*)d_in[2];
    const float* bmu  = (const float*)d_in[3];
    const float* brho = (const float*)d_in[4];
    const float* ew   = (const float*)d_in[5];
    const float* eb   = (const float*)d_in[6];
    float* out = (float*)d_out;

    const int Nout = in_sizes[3];            // 4096
    const int K    = in_sizes[1] / Nout;     // 4096
    const int M    = in_sizes[0] / K;        // 16384

    u16* xb = (u16*)d_ws;
    u16* wb = xb + (size_t)M * K;
    float* bs = (float*)(wb + (size_t)Nout * K);

    const int nx4 = (M * K) / 4;
    const int nw4 = (Nout * K) / 4;
    prep_x_kernel<<<(nx4 + 255) / 256, 256, 0, stream>>>(x, xb, nx4);
    prep_w_kernel<<<(nw4 + 255) / 256, 256, 0, stream>>>(wmu, wrho, ew, wb, nw4);
    prep_bias_kernel<<<(Nout + 255) / 256, 256, 0, stream>>>(bmu, brho, eb, bs, Nout);

    dim3 grid((M / 256) * (Nout / 256));
    gemm256_8ph<<<grid, 512, 0, stream>>>(xb, wb, bs, out, M, Nout, K);
}

// Round 3
// 567.568 us; speedup vs baseline: 1.3009x; 1.0085x over previous
//
#include <hip/hip_runtime.h>
#include <hip/hip_bf16.h>

typedef unsigned short u16;
typedef __attribute__((ext_vector_type(4))) float f32x4;
typedef __attribute__((ext_vector_type(8))) short bf16x8;

// ---------------------------------------------------------------------------
// helpers
// ---------------------------------------------------------------------------
__device__ __forceinline__ u16 f2bf(float f) {
    union { float f; unsigned u; } v; v.f = f;
    unsigned r = (v.u + 0x7fffu + ((v.u >> 16) & 1u)) >> 16;   // RNE
    return (u16)r;
}

__device__ __forceinline__ float softplus(float x) {
    return (x > 15.f) ? x : log1pf(__expf(x));
}

__device__ __forceinline__ void gload_lds16(const void* g, void* l) {
    __builtin_amdgcn_global_load_lds(
        (__attribute__((address_space(1))) void*)(g),
        (__attribute__((address_space(3))) void*)(l),
        16, 0, 0);
}

#define BAR() do { asm volatile("" ::: "memory"); \
                   __builtin_amdgcn_s_barrier();  \
                   asm volatile("" ::: "memory"); } while (0)

// ---------------------------------------------------------------------------
// prep kernels (BW-roofline already)
// ---------------------------------------------------------------------------
__global__ __launch_bounds__(256) void prep_x_kernel(
        const float* __restrict__ x, u16* __restrict__ xb, int n4) {
    int i = blockIdx.x * 256 + threadIdx.x;
    if (i >= n4) return;
    float4 v = ((const float4*)x)[i];
    ushort4 o;
    o.x = f2bf(v.x); o.y = f2bf(v.y); o.z = f2bf(v.z); o.w = f2bf(v.w);
    ((ushort4*)xb)[i] = o;
}

__global__ __launch_bounds__(256) void prep_w_kernel(
        const float* __restrict__ mu, const float* __restrict__ rho,
        const float* __restrict__ eps, u16* __restrict__ wb, int n4) {
    int i = blockIdx.x * 256 + threadIdx.x;
    if (i >= n4) return;
    float4 m = ((const float4*)mu)[i];
    float4 r = ((const float4*)rho)[i];
    float4 e = ((const float4*)eps)[i];
    ushort4 o;
    o.x = f2bf(m.x + softplus(r.x) * e.x);
    o.y = f2bf(m.y + softplus(r.y) * e.y);
    o.z = f2bf(m.z + softplus(r.z) * e.z);
    o.w = f2bf(m.w + softplus(r.w) * e.w);
    ((ushort4*)wb)[i] = o;
}

__global__ __launch_bounds__(256) void prep_bias_kernel(
        const float* __restrict__ mu, const float* __restrict__ rho,
        const float* __restrict__ eps, float* __restrict__ b, int n) {
    int i = blockIdx.x * 256 + threadIdx.x;
    if (i < n) b[i] = mu[i] + softplus(rho[i]) * eps[i];
}

// ---------------------------------------------------------------------------
// 256x256 8-phase bf16 GEMM (B^T) + bias.  Read-balanced schedule:
// per-phase ds_read counts 4/4/8/8 (was 12/4/8/0); the 8-read bursts for the
// next buffer sit AFTER the vmcnt(4)+BAR+MFMA of PH4/PH8, hidden under that
// phase's MFMA drain. Staging plan / vmcnt schedule / swizzle unchanged.
// ---------------------------------------------------------------------------
__device__ __forceinline__ bf16x8 ld_frag(const u16* region, int r0, int ks, int lane) {
    int row = r0 + (lane & 15);
    int kc  = (ks * 4 + (lane >> 4)) ^ (row & 7);
    return *(const bf16x8*)((const char*)region + row * 128 + kc * 16);
}

template <int MB, int NB>
__device__ __forceinline__ void mfma_quad(f32x4 (&acc)[8][4],
                                          const bf16x8 (&av)[4][2],
                                          const bf16x8 (&bv)[2][2]) {
#pragma unroll
    for (int ks = 0; ks < 2; ++ks)
#pragma unroll
        for (int mi = 0; mi < 4; ++mi)
#pragma unroll
            for (int ni = 0; ni < 2; ++ni)
                acc[MB + mi][NB + ni] = __builtin_amdgcn_mfma_f32_16x16x32_bf16(
                    av[mi][ks], bv[ni][ks], acc[MB + mi][NB + ni], 0, 0, 0);
}

#define STAGE(region, h, P, koff) do {                                          \
    gload_lds16(P[h][0] + (koff), (char*)(region) + (h) * 16384 + (w * 2 + 0) * 1024); \
    gload_lds16(P[h][1] + (koff), (char*)(region) + (h) * 16384 + (w * 2 + 1) * 1024); \
} while (0)

#define RD_A(reg, roff)                                                \
    _Pragma("unroll")                                                  \
    for (int mi = 0; mi < 4; ++mi)                                     \
        _Pragma("unroll")                                              \
        for (int ks = 0; ks < 2; ++ks)                                 \
            a[mi][ks] = ld_frag(reg, wr * 128 + (roff) + mi * 16, ks, lane)

#define RD_B(dst, reg, roff)                                           \
    _Pragma("unroll")                                                  \
    for (int ni = 0; ni < 2; ++ni)                                     \
        _Pragma("unroll")                                              \
        for (int ks = 0; ks < 2; ++ks)                                 \
            dst[ni][ks] = ld_frag(reg, wc * 64 + (roff) + ni * 16, ks, lane)

__global__ __launch_bounds__(512, 2) void gemm256_8ph(
        const u16* __restrict__ A,   // [M][K] bf16
        const u16* __restrict__ B,   // [Nout][K] bf16
        const float* __restrict__ bias,
        float* __restrict__ C,       // [M][Nout] fp32
        int M, int Nout, int K) {
    __shared__ __attribute__((aligned(16))) u16 smem[4][16384];  // A0,B0,A1,B1
    u16* A0 = smem[0]; u16* B0 = smem[1];
    u16* A1 = smem[2]; u16* B1 = smem[3];

    const int tid  = threadIdx.x;
    const int lane = tid & 63;
    const int w    = tid >> 6;     // wave 0..7
    const int wr   = w >> 2;       // 0..1 -> 128-row slice
    const int wc   = w & 3;        // 0..3 -> 64-col slice

    // bijective XCD swizzle (nwg % 8 == 0 here)
    const int nbn = Nout >> 8;
    const int nwg = (M >> 8) * nbn;
    const int cpx = nwg >> 3;
    const int swz = ((int)blockIdx.x & 7) * cpx + ((int)blockIdx.x >> 3);
    const int m0 = (swz / nbn) << 8;
    const int n0 = (swz % nbn) << 8;

    // per-thread staging source pointers (inverse-swizzled global chunks)
    const u16* PA[2][2]; const u16* PB[2][2];
#pragma unroll
    for (int q = 0; q < 2; ++q) {
        int c   = (w * 2 + q) * 64 + lane;
        int row = c >> 3;
        int kc  = (c & 7) ^ (row & 7);
#pragma unroll
        for (int h = 0; h < 2; ++h) {
            PA[h][q] = A + (size_t)(m0 + h * 128 + row) * K + kc * 8;
            PB[h][q] = B + (size_t)(n0 + h * 128 + row) * K + kc * 8;
        }
    }

    bf16x8 a[4][2], bl[2][2], bh[2][2];
    f32x4 acc[8][4] = {};

    const int NT = K >> 6;    // K-tiles
    const int NI = NT >> 1;   // iterations (2 tiles each)

    // prologue: tile0 -> buf0 (all), tile1 -> buf1 (B units)
    STAGE(B0, 0, PB, 0);  STAGE(B0, 1, PB, 0);
    STAGE(A0, 0, PA, 0);  STAGE(A0, 1, PA, 0);
    STAGE(B1, 0, PB, 64); STAGE(B1, 1, PB, 64);
    asm volatile("s_waitcnt vmcnt(4)" ::: "memory");   // tile0 landed
    BAR();
    RD_A(A0, 0);   // al pre-read for PH1 (matches PH8-exit state)

#pragma unroll 1
    for (int i = 0; i < NI; ++i) {
        int t2 = 2 * i + 2; if (t2 >= NT) t2 -= NT;
        int t3 = 2 * i + 3; if (t3 >= NT) t3 -= NT;
        const int k1 = (2 * i + 1) << 6;
        const int k2 = t2 << 6;
        const int k3 = t3 << 6;

        // -------- PH1: q0 = al x bl          | reads bl(4) | stage A1-lo(t1)
        RD_B(bl, B0, 0);
        STAGE(A1, 0, PA, k1);
        BAR();
        asm volatile("s_waitcnt lgkmcnt(0)" ::: "memory");
        __builtin_amdgcn_s_setprio(1);
        mfma_quad<0, 0>(acc, a, bl);
        __builtin_amdgcn_s_setprio(0);
        BAR();

        // -------- PH2: q1 = al x bh          | reads bh(4) | stage A1-hi(t1)
        RD_B(bh, B0, 32);
        STAGE(A1, 1, PA, k1);
        BAR();
        asm volatile("s_waitcnt lgkmcnt(0)" ::: "memory");
        __builtin_amdgcn_s_setprio(1);
        mfma_quad<0, 2>(acc, a, bh);
        __builtin_amdgcn_s_setprio(0);
        BAR();

        // -------- PH3: q2 = ah x bh          | reads ah(8) | stage B0-lo(t2)
        RD_A(A0, 64);
        STAGE(B0, 0, PB, k2);
        BAR();
        asm volatile("s_waitcnt lgkmcnt(0)" ::: "memory");
        __builtin_amdgcn_s_setprio(1);
        mfma_quad<4, 2>(acc, a, bh);
        __builtin_amdgcn_s_setprio(0);
        BAR();

        // -------- PH4: q3 = ah x bl | stage B0-hi(t2) | vmcnt(4): t1 landed
        //          then read al'(8) from A1 (hidden under q3's MFMA drain)
        STAGE(B0, 1, PB, k2);
        asm volatile("s_waitcnt vmcnt(4)" ::: "memory");
        BAR();
        __builtin_amdgcn_s_setprio(1);
        mfma_quad<4, 0>(acc, a, bl);
        __builtin_amdgcn_s_setprio(0);
        RD_A(A1, 0);
        BAR();

        // -------- PH5: q0' = al' x bl'       | reads bl'(4) | stage A0-lo(t2)
        RD_B(bl, B1, 0);
        STAGE(A0, 0, PA, k2);
        BAR();
        asm volatile("s_waitcnt lgkmcnt(0)" ::: "memory");
        __builtin_amdgcn_s_setprio(1);
        mfma_quad<0, 0>(acc, a, bl);
        __builtin_amdgcn_s_setprio(0);
        BAR();

        // -------- PH6: q1' = al' x bh'       | reads bh'(4) | stage A0-hi(t2)
        RD_B(bh, B1, 32);
        STAGE(A0, 1, PA, k2);
        BAR();
        asm volatile("s_waitcnt lgkmcnt(0)" ::: "memory");
        __builtin_amdgcn_s_setprio(1);
        mfma_quad<0, 2>(acc, a, bh);
        __builtin_amdgcn_s_setprio(0);
        BAR();

        // -------- PH7: q2' = ah' x bh'       | reads ah'(8) | stage B1-lo(t3)
        RD_A(A1, 64);
        STAGE(B1, 0, PB, k3);
        BAR();
        asm volatile("s_waitcnt lgkmcnt(0)" ::: "memory");
        __builtin_amdgcn_s_setprio(1);
        mfma_quad<4, 2>(acc, a, bh);
        __builtin_amdgcn_s_setprio(0);
        BAR();

        // -------- PH8: q3' = ah' x bl' | stage B1-hi(t3) | vmcnt(4): t2 landed
        //          then read al''(8) from A0 for next iteration's PH1
        STAGE(B1, 1, PB, k3);
        asm volatile("s_waitcnt vmcnt(4)" ::: "memory");
        BAR();
        __builtin_amdgcn_s_setprio(1);
        mfma_quad<4, 0>(acc, a, bl);
        __builtin_amdgcn_s_setprio(0);
        RD_A(A0, 0);
        BAR();
    }

    asm volatile("s_waitcnt vmcnt(0)" ::: "memory");  // drain wrapped prefetch

    // epilogue: C/D layout col = lane&15, row = (lane>>4)*4 + q
    const int crow = (lane >> 4) * 4;
    const int ccol = lane & 15;
#pragma unroll
    for (int mi = 0; mi < 8; ++mi) {
#pragma unroll
        for (int ni = 0; ni < 4; ++ni) {
            const int row = m0 + wr * 128 + mi * 16 + crow;
            const int col = n0 + wc * 64 + ni * 16 + ccol;
            const float bv = bias[col];
            float* Cp = C + (size_t)row * Nout + col;
#pragma unroll
            for (int q = 0; q < 4; ++q)
                Cp[(size_t)q * Nout] = acc[mi][ni][q] + bv;
        }
    }
}

// ---------------------------------------------------------------------------
// launch
// ---------------------------------------------------------------------------
extern "C" void kernel_launch(void* const* d_in, const int* in_sizes, int n_in,
                              void* d_out, int out_size, void* d_ws, size_t ws_size,
                              hipStream_t stream) {
    const float* x    = (const float*)d_in[0];
    const float* wmu  = (const float*)d_in[1];
    const float* wrho = (const float*)d_in[2];
    const float* bmu  = (const float*)d_in[3];
    const float* brho = (const float*)d_in[4];
    const float* ew   = (const float*)d_in[5];
    const float* eb   = (const float*)d_in[6];
    float* out = (float*)d_out;

    const int Nout = in_sizes[3];            // 4096
    const int K    = in_sizes[1] / Nout;     // 4096
    const int M    = in_sizes[0] / K;        // 16384

    u16* xb = (u16*)d_ws;
    u16* wb = xb + (size_t)M * K;
    float* bs = (float*)(wb + (size_t)Nout * K);

    const int nx4 = (M * K) / 4;
    const int nw4 = (Nout * K) / 4;
    prep_x_kernel<<<(nx4 + 255) / 256, 256, 0, stream>>>(x, xb, nx4);
    prep_w_kernel<<<(nw4 + 255) / 256, 256, 0, stream>>>(wmu, wrho, ew, wb, nw4);
    prep_bias_kernel<<<(Nout + 255) / 256, 256, 0, stream>>>(bmu, brho, eb, bs, Nout);

    dim3 grid((M / 256) * (Nout / 256));
    gemm256_8ph<<<grid, 512, 0, stream>>>(xb, wb, bs, out, M, Nout, K);
}